// Round 2
// baseline (681.054 us; speedup 1.0000x reference)
//
#include <hip/hip_runtime.h>
#include <cstdint>
#include <cstddef>

typedef __attribute__((ext_vector_type(8))) short short8;
typedef __attribute__((ext_vector_type(4))) float f32x4;

#define DEV __device__ __forceinline__

DEV unsigned short f2bf(float f) {
  unsigned int u = __float_as_uint(f);
  u += 0x7fffu + ((u >> 16) & 1u);   // round-to-nearest-even
  return (unsigned short)(u >> 16);
}

constexpr int NROW = 12288;

// ---------------- P0: t0T = (x @ W0)^T  -> bf16 [128][12288] ----------------
__global__ __launch_bounds__(256) void xw_kernel(
    const float* __restrict__ x, const float* __restrict__ W0,
    unsigned short* __restrict__ t0T) {
  __shared__ float sW[128 * 128];
  __shared__ float sx[16][128];
  const int t = threadIdx.x;
  for (int i = t; i < 128 * 128; i += 256) sW[i] = W0[i];
  const int r0 = blockIdx.x * 16;
  for (int i = t; i < 16 * 128; i += 256)
    sx[i >> 7][i & 127] = x[(size_t)(r0 + (i >> 7)) * 128 + (i & 127)];
  __syncthreads();
  const int c = t & 127;   // output column 0..127
  const int rg = t >> 7;   // row group: rows rg*8 .. rg*8+7
  float acc[8] = {0, 0, 0, 0, 0, 0, 0, 0};
  for (int k = 0; k < 128; ++k) {
    float w = sW[k * 128 + c];
#pragma unroll
    for (int j = 0; j < 8; ++j) acc[j] += sx[rg * 8 + j][k] * w;
  }
  uint4 o;
  unsigned int p[4];
#pragma unroll
  for (int q = 0; q < 4; ++q)
    p[q] = (unsigned int)f2bf(acc[2 * q]) |
           ((unsigned int)f2bf(acc[2 * q + 1]) << 16);
  o.x = p[0]; o.y = p[1]; o.z = p[2]; o.w = p[3];
  *(uint4*)(t0T + (size_t)c * NROW + r0 + rg * 8) = o;
}

// ------------- big GEMM: part[split] = adj_chunk @ t   (bf16 MFMA) -----------
// A: [12288][12288] f32 (adj), BT: [H][12288] bf16 (t transposed)
// part: [KSPLIT][12288][H] f32 partial sums
// Pipeline: A (HBM) loads 2 steps ahead in named reg sets av0/av1; B (L2)
// loads 1 step ahead, issued BEFORE the next A set so the lstore waitcnt is
// a counted vmcnt that keeps the next-next A tile in flight across the
// barrier (in-order vmcnt completion).
template <int H>
__global__ __launch_bounds__(256, 3) void gcn_gemm(
    const float* __restrict__ A, const unsigned short* __restrict__ BT,
    float* __restrict__ part) {
  constexpr int KSPLIT = 4;
  constexpr int BM = 64, BK = 64;
  constexpr int WN = (H >= 64) ? 2 : 1;
  constexpr int WM = 4 / WN;
  constexpr int MR = BM / (WM * 16);
  constexpr int NR = H / (WN * 16);
  constexpr int NB = H / 32;                    // B staging rounds
  constexpr int KSTEPS = (NROW / KSPLIT) / BK;  // 48 (even)
  constexpr int BBYTES = H * 128;               // one B^T tile (bf16)

  __shared__ alignas(16) char lds[16384 + 2 * BBYTES];
  char* ldsB = lds + 16384;

  const int t = threadIdx.x;
  const int nmb = NROW / BM;  // 192
  const int bm = blockIdx.x % nmb;
  const int split = blockIdx.x / nmb;
  const int k0 = split * (NROW / KSPLIT);

  // ---- A staging: thread loads 4x float4 (rows mA+16i, cols kA..kA+3) ----
  const int mA = t >> 4;
  const int kA = (t & 15) * 4;
  const float* aptr = A + (size_t)(bm * BM + mA) * NROW + k0 + kA;
  int aw[4];
#pragma unroll
  for (int i = 0; i < 4; ++i) {
    int row = i * 16 + mA;
    aw[i] = ((row * 128) + kA * 2) ^ ((row & 7) << 4);  // swizzled byte off
  }

  // ---- B^T staging: linear LDS dest, swizzle folded into global source ----
  const int nB0 = t >> 3;                    // row within round (+32/round)
  const int wB = (t & 7) ^ (nB0 & 7);        // pre-swizzled 16B chunk in row
  const unsigned short* bptr = BT + (size_t)nB0 * NROW + k0 + wB * 8;

  // ---- MFMA fragment LDS offsets ----
  const int wid = t >> 6;
  const int lane = t & 63;
  const int l15 = lane & 15;
  const int loct = lane >> 4;
  const int wm = wid / WN;
  const int wn = wid % WN;
  int aoff[MR][2], boff[NR][2];
#pragma unroll
  for (int m = 0; m < MR; ++m)
#pragma unroll
    for (int kk = 0; kk < 2; ++kk) {
      int row = wm * (MR * 16) + m * 16 + l15;
      aoff[m][kk] = (row * 128 + kk * 64 + loct * 16) ^ ((row & 7) << 4);
    }
#pragma unroll
  for (int n = 0; n < NR; ++n)
#pragma unroll
    for (int kk = 0; kk < 2; ++kk) {
      int nn = wn * (NR * 16) + n * 16 + l15;
      boff[n][kk] = (nn * 128 + kk * 64 + loct * 16) ^ ((nn & 7) << 4);
    }

  f32x4 acc[MR][NR];
#pragma unroll
  for (int m = 0; m < MR; ++m)
#pragma unroll
    for (int n = 0; n < NR; ++n) acc[m][n] = {0.f, 0.f, 0.f, 0.f};

  float4 av0[4], av1[4];
  uint4 bv[NB];

  auto gloadA = [&](float4* av, int s) {
    if (s >= KSTEPS) return;
#pragma unroll
    for (int i = 0; i < 4; ++i)
      av[i] = *(const float4*)(aptr + (size_t)i * 16 * NROW + s * BK);
  };
  auto gloadB = [&](int s) {
    if (s >= KSTEPS) return;
#pragma unroll
    for (int j = 0; j < NB; ++j)
      bv[j] = *(const uint4*)(bptr + (size_t)j * 32 * NROW + s * BK);
  };
  auto lstore = [&](const float4* av, int buf) {
    char* lA = lds + buf * 8192;
#pragma unroll
    for (int i = 0; i < 4; ++i) {
      uint2 w;
      w.x = (unsigned int)f2bf(av[i].x) | ((unsigned int)f2bf(av[i].y) << 16);
      w.y = (unsigned int)f2bf(av[i].z) | ((unsigned int)f2bf(av[i].w) << 16);
      *(uint2*)(lA + aw[i]) = w;
    }
    char* lB = ldsB + buf * BBYTES;
#pragma unroll
    for (int j = 0; j < NB; ++j) *(uint4*)(lB + j * 4096 + t * 16) = bv[j];
  };
  auto compute = [&](int buf) {
    const char* lA = lds + buf * 8192;
    const char* lB = ldsB + buf * BBYTES;
#pragma unroll
    for (int kk = 0; kk < 2; ++kk) {
      short8 af[MR], bfv[NR];
#pragma unroll
      for (int m = 0; m < MR; ++m) af[m] = *(const short8*)(lA + aoff[m][kk]);
#pragma unroll
      for (int n = 0; n < NR; ++n) bfv[n] = *(const short8*)(lB + boff[n][kk]);
#pragma unroll
      for (int m = 0; m < MR; ++m)
#pragma unroll
        for (int n = 0; n < NR; ++n)
          acc[m][n] = __builtin_amdgcn_mfma_f32_16x16x32_bf16(
              af[m], bfv[n], acc[m][n], 0, 0, 0);
    }
  };

  // Prologue: buf0 <- step0; av1 <- step1 (in flight).
  gloadA(av0, 0);
  gloadB(0);
  lstore(av0, 0);   // vmcnt(0) — prologue only
  gloadA(av1, 1);
  __syncthreads();

  static_assert((KSTEPS & 1) == 0, "KSTEPS must be even");
  for (int s = 0; s < KSTEPS; s += 2) {
    // even iter s: compute buf0(step s); av1 holds s+1
    gloadB(s + 1);            // B for s+1 (issued before next A set)
    gloadA(av0, s + 2);       // A 2 ahead — stays in flight across barrier
    compute(0);
    lstore(av1, 1);           // counted vmcnt: waits B(s+1), not A(s+2)
    __syncthreads();
    // odd iter s+1: compute buf1(step s+1); av0 holds s+2
    gloadB(s + 2);
    gloadA(av1, s + 3);
    compute(1);
    if (s + 2 < KSTEPS) {
      lstore(av0, 0);
      __syncthreads();
    }
  }

  float* pout = part + ((size_t)split * NROW + (size_t)bm * BM) * H;
#pragma unroll
  for (int m = 0; m < MR; ++m) {
    const int row = wm * (MR * 16) + m * 16 + loct * 4;
#pragma unroll
    for (int n = 0; n < NR; ++n) {
      const int col = wn * (NR * 16) + n * 16 + l15;
#pragma unroll
      for (int r = 0; r < 4; ++r)
        pout[(size_t)(row + r) * H + col] = acc[m][n][r];
    }
  }
}

// ------- reduce: sum splits + bias + LN + (leaky) + @Wnext -> t_next^T -------
template <int H, int H2, bool ACT>
__global__ __launch_bounds__(256) void reduce_ln(
    const float* __restrict__ part, const float* __restrict__ bias,
    const float* __restrict__ g, const float* __restrict__ be,
    const float* __restrict__ Wn, unsigned short* __restrict__ tT) {
  __shared__ float sW[H * H2];
  __shared__ float sh[4][H];
  const int t = threadIdx.x;
  for (int i = t; i < H * H2; i += 256) sW[i] = Wn[i];
  __syncthreads();

  const int wid = t >> 6, lane = t & 63;
  const int row = blockIdx.x * 4 + wid;
  constexpr int CPL = H / 64;
  float v[CPL];
#pragma unroll
  for (int c = 0; c < CPL; ++c) {
    const int col = lane + c * 64;
    float s = bias[col];
#pragma unroll
    for (int sp = 0; sp < 4; ++sp)
      s += part[((size_t)sp * NROW + row) * H + col];
    v[c] = s;
  }
  float sum = 0;
#pragma unroll
  for (int c = 0; c < CPL; ++c) sum += v[c];
#pragma unroll
  for (int o = 32; o > 0; o >>= 1) sum += __shfl_xor(sum, o);
  const float mu = sum / H;
  float vs = 0;
#pragma unroll
  for (int c = 0; c < CPL; ++c) { float d = v[c] - mu; vs += d * d; }
#pragma unroll
  for (int o = 32; o > 0; o >>= 1) vs += __shfl_xor(vs, o);
  const float rstd = rsqrtf(vs / H + 1e-5f);
#pragma unroll
  for (int c = 0; c < CPL; ++c) {
    const int col = lane + c * 64;
    float h = (v[c] - mu) * rstd * g[col] + be[col];
    if (ACT) h = (h > 0.f) ? h : 0.01f * h;
    sh[wid][col] = h;
  }
  __syncthreads();
  if (lane < H2) {
    float d = 0;
#pragma unroll 8
    for (int k = 0; k < H; ++k) d += sh[wid][k] * sW[k * H2 + lane];
    tT[(size_t)lane * NROW + row] = f2bf(d);
  }
}

// ------- final: sum splits + bias + LN + leaky + @Wl+bl + log_softmax -------
__global__ __launch_bounds__(256) void reduce_final(
    const float* __restrict__ part, const float* __restrict__ bias,
    const float* __restrict__ g, const float* __restrict__ be,
    const float* __restrict__ Wl, const float* __restrict__ bl,
    float* __restrict__ out) {
  __shared__ float sW[32 * 20];
  __shared__ float sbl[20];
  __shared__ float sh[4][32];
  __shared__ float sl[4][20];
  const int t = threadIdx.x;
  for (int i = t; i < 640; i += 256) sW[i] = Wl[i];
  if (t < 20) sbl[t] = bl[t];
  __syncthreads();
  const int wid = t >> 6, lane = t & 63;
  const int row = blockIdx.x * 4 + wid;
  const int col = lane & 31;  // lanes 32..63 duplicate cols 0..31
  float v = bias[col];
#pragma unroll
  for (int sp = 0; sp < 4; ++sp)
    v += part[((size_t)sp * NROW + row) * 32 + col];
  float sum = v;
#pragma unroll
  for (int o = 32; o > 0; o >>= 1) sum += __shfl_xor(sum, o);
  const float mu = sum / 64.f;  // values duplicated 2x across the wave
  float d0 = v - mu;
  float vs = d0 * d0;
#pragma unroll
  for (int o = 32; o > 0; o >>= 1) vs += __shfl_xor(vs, o);
  const float rstd = rsqrtf(vs / 64.f + 1e-5f);
  float h = (v - mu) * rstd * g[col] + be[col];
  h = (h > 0.f) ? h : 0.01f * h;
  if (lane < 32) sh[wid][col] = h;
  __syncthreads();
  if (lane < 20) {
    float lg = sbl[lane];
#pragma unroll
    for (int k = 0; k < 32; ++k) lg += sh[wid][k] * sW[k * 20 + lane];
    sl[wid][lane] = lg;
  }
  __syncthreads();
  if (lane < 20) {
    float mx = -1e30f;
#pragma unroll
    for (int k = 0; k < 20; ++k) mx = fmaxf(mx, sl[wid][k]);
    float se = 0.f;
#pragma unroll
    for (int k = 0; k < 20; ++k) se += expf(sl[wid][k] - mx);
    out[(size_t)row * 20 + lane] = sl[wid][lane] - mx - logf(se);
  }
}

extern "C" void kernel_launch(void* const* d_in, const int* in_sizes, int n_in,
                              void* d_out, int out_size, void* d_ws,
                              size_t ws_size, hipStream_t stream) {
  const float* x    = (const float*)d_in[0];
  const float* adj0 = (const float*)d_in[1];
  const float* adj1 = (const float*)d_in[2];
  const float* adj2 = (const float*)d_in[3];
  const float* W0   = (const float*)d_in[4];
  const float* b0   = (const float*)d_in[5];
  const float* W1   = (const float*)d_in[6];
  const float* b1   = (const float*)d_in[7];
  const float* W2   = (const float*)d_in[8];
  const float* b2   = (const float*)d_in[9];
  const float* g0   = (const float*)d_in[10];
  const float* be0  = (const float*)d_in[11];
  const float* g1   = (const float*)d_in[12];
  const float* be1  = (const float*)d_in[13];
  const float* g2   = (const float*)d_in[14];
  const float* be2  = (const float*)d_in[15];
  const float* Wl   = (const float*)d_in[16];
  const float* bl   = (const float*)d_in[17];
  float* out = (float*)d_out;

  char* ws = (char*)d_ws;
  float* part =          (float*)(ws);                      // 4*12288*128*4 = 25165824 B
  unsigned short* t0T = (unsigned short*)(ws + 25165824);   // 128*12288*2 = 3145728 B
  unsigned short* t1T = (unsigned short*)(ws + 25165824 + 3145728);          // 1572864 B
  unsigned short* t2T = (unsigned short*)(ws + 25165824 + 3145728 + 1572864); // 786432 B

  xw_kernel<<<NROW / 16, 256, 0, stream>>>(x, W0, t0T);
  gcn_gemm<128><<<(NROW / 64) * 4, 256, 0, stream>>>(adj0, t0T, part);
  reduce_ln<128, 64, false><<<NROW / 4, 256, 0, stream>>>(part, b0, g0, be0, W1, t1T);
  gcn_gemm<64><<<(NROW / 64) * 4, 256, 0, stream>>>(adj1, t1T, part);
  reduce_ln<64, 32, true><<<NROW / 4, 256, 0, stream>>>(part, b1, g1, be1, W2, t2T);
  gcn_gemm<32><<<(NROW / 64) * 4, 256, 0, stream>>>(adj2, t2T, part);
  reduce_final<<<NROW / 4, 256, 0, stream>>>(part, b2, g2, be2, Wl, bl, out);
}

// Round 3
// 483.539 us; speedup vs baseline: 1.4085x; 1.4085x over previous
//
#include <hip/hip_runtime.h>
#include <cstdint>
#include <cstddef>

typedef __attribute__((ext_vector_type(8))) short short8;
typedef __attribute__((ext_vector_type(4))) float f32x4;

#define DEV __device__ __forceinline__

DEV unsigned short f2bf(float f) {
  unsigned int u = __float_as_uint(f);
  u += 0x7fffu + ((u >> 16) & 1u);   // round-to-nearest-even
  return (unsigned short)(u >> 16);
}

// async 16B global -> LDS (wave-uniform LDS base; HW adds lane*16)
DEV void glds16(const void* g, void* l) {
  __builtin_amdgcn_global_load_lds(
      (const __attribute__((address_space(1))) void*)g,
      (__attribute__((address_space(3))) void*)l, 16, 0, 0);
}

constexpr int NROW = 12288;

// ---------------- P0: t0T = (x @ W0)^T  -> bf16 [128][12288] ----------------
__global__ __launch_bounds__(256) void xw_kernel(
    const float* __restrict__ x, const float* __restrict__ W0,
    unsigned short* __restrict__ t0T) {
  __shared__ float sW[128 * 128];
  __shared__ float sx[16][128];
  const int t = threadIdx.x;
  for (int i = t; i < 128 * 128; i += 256) sW[i] = W0[i];
  const int r0 = blockIdx.x * 16;
  for (int i = t; i < 16 * 128; i += 256)
    sx[i >> 7][i & 127] = x[(size_t)(r0 + (i >> 7)) * 128 + (i & 127)];
  __syncthreads();
  const int c = t & 127;   // output column 0..127
  const int rg = t >> 7;   // row group: rows rg*8 .. rg*8+7
  float acc[8] = {0, 0, 0, 0, 0, 0, 0, 0};
  for (int k = 0; k < 128; ++k) {
    float w = sW[k * 128 + c];
#pragma unroll
    for (int j = 0; j < 8; ++j) acc[j] += sx[rg * 8 + j][k] * w;
  }
  uint4 o;
  unsigned int p[4];
#pragma unroll
  for (int q = 0; q < 4; ++q)
    p[q] = (unsigned int)f2bf(acc[2 * q]) |
           ((unsigned int)f2bf(acc[2 * q + 1]) << 16);
  o.x = p[0]; o.y = p[1]; o.z = p[2]; o.w = p[3];
  *(uint4*)(t0T + (size_t)c * NROW + r0 + rg * 8) = o;
}

// ------------- big GEMM: part[split] = adj_chunk @ t   (bf16 MFMA) -----------
// A: [12288][12288] f32 (adj), BT: [H][12288] bf16 (t transposed)
// part: [KSPLIT][12288][H] f32 partial sums
// Pipeline (raw-barrier, counted vmcnt — T3/T4):
//   B(s+1): global_load_lds direct (linear LDS dest, swizzle pre-folded into
//           the per-lane global source address).
//   A(s+2): register 2-ahead (av0/av1 named sets), f2bf convert + swizzled
//           ds_write one iter later.
//   Before each barrier: s_waitcnt vmcnt(4) lgkmcnt(0) — retires B-DMA and
//   A ds_writes, leaves the 4 newest A loads in flight ACROSS the barrier.
template <int H>
__global__ __launch_bounds__(256, 3) void gcn_gemm(
    const float* __restrict__ A, const unsigned short* __restrict__ BT,
    float* __restrict__ part) {
  constexpr int KSPLIT = 4;
  constexpr int BM = 64, BK = 64;
  constexpr int WN = (H >= 64) ? 2 : 1;
  constexpr int WM = 4 / WN;
  constexpr int MR = BM / (WM * 16);
  constexpr int NR = H / (WN * 16);
  constexpr int NB = H / 32;                    // B DMA rounds (per thread)
  constexpr int KSTEPS = (NROW / KSPLIT) / BK;  // 48 (even)
  constexpr int BBYTES = H * 128;               // one B^T tile (bf16)

  __shared__ alignas(16) char lds[16384 + 2 * BBYTES];
  char* ldsB = lds + 16384;

  const int t = threadIdx.x;
  const int nmb = NROW / BM;  // 192
  const int bm = blockIdx.x % nmb;
  const int split = blockIdx.x / nmb;
  const int k0 = split * (NROW / KSPLIT);

  // ---- A staging: thread loads 4x float4 (rows mA+16i, cols kA..kA+3) ----
  const int mA = t >> 4;
  const int kA = (t & 15) * 4;
  const float* aptr = A + (size_t)(bm * BM + mA) * NROW + k0 + kA;
  int aw[4];
#pragma unroll
  for (int i = 0; i < 4; ++i) {
    int row = i * 16 + mA;
    aw[i] = ((row * 128) + kA * 2) ^ ((row & 7) << 4);  // swizzled byte off
  }

  // ---- B^T staging source: swizzle folded into global address ----
  const int nB0 = t >> 3;                    // row within round (+32/round)
  const int wB = (t & 7) ^ (nB0 & 7);        // pre-swizzled 16B chunk in row
  const unsigned short* bptr = BT + (size_t)nB0 * NROW + k0 + wB * 8;
  const int wid = t >> 6;
  // wave-uniform LDS dest base for B DMA: + j*4096 + wid*1024 (+ lane*16 by HW)
  char* ldsBw = ldsB + wid * 1024;

  // ---- MFMA fragment LDS offsets ----
  const int lane = t & 63;
  const int l15 = lane & 15;
  const int loct = lane >> 4;
  const int wm = wid / WN;
  const int wn = wid % WN;
  int aoff[MR][2], boff[NR][2];
#pragma unroll
  for (int m = 0; m < MR; ++m)
#pragma unroll
    for (int kk = 0; kk < 2; ++kk) {
      int row = wm * (MR * 16) + m * 16 + l15;
      aoff[m][kk] = (row * 128 + kk * 64 + loct * 16) ^ ((row & 7) << 4);
    }
#pragma unroll
  for (int n = 0; n < NR; ++n)
#pragma unroll
    for (int kk = 0; kk < 2; ++kk) {
      int nn = wn * (NR * 16) + n * 16 + l15;
      boff[n][kk] = (nn * 128 + kk * 64 + loct * 16) ^ ((nn & 7) << 4);
    }

  f32x4 acc[MR][NR];
#pragma unroll
  for (int m = 0; m < MR; ++m)
#pragma unroll
    for (int n = 0; n < NR; ++n) acc[m][n] = {0.f, 0.f, 0.f, 0.f};

  float4 av0[4], av1[4];

  auto gloadA = [&](float4* av, int s) {
#pragma unroll
    for (int i = 0; i < 4; ++i)
      av[i] = *(const float4*)(aptr + (size_t)i * 16 * NROW + s * BK);
  };
  auto glB = [&](int s, int buf) {
#pragma unroll
    for (int j = 0; j < NB; ++j)
      glds16(bptr + (size_t)j * 32 * NROW + s * BK,
             ldsBw + buf * BBYTES + j * 4096);
  };
  auto lstoreA = [&](const float4* av, int buf) {
    char* lA = lds + buf * 8192;
#pragma unroll
    for (int i = 0; i < 4; ++i) {
      uint2 w;
      w.x = (unsigned int)f2bf(av[i].x) | ((unsigned int)f2bf(av[i].y) << 16);
      w.y = (unsigned int)f2bf(av[i].z) | ((unsigned int)f2bf(av[i].w) << 16);
      *(uint2*)(lA + aw[i]) = w;
    }
  };
  auto compute = [&](int buf) {
    const char* lA = lds + buf * 8192;
    const char* lB = ldsB + buf * BBYTES;
#pragma unroll
    for (int kk = 0; kk < 2; ++kk) {
      short8 af[MR], bfv[NR];
#pragma unroll
      for (int m = 0; m < MR; ++m) af[m] = *(const short8*)(lA + aoff[m][kk]);
#pragma unroll
      for (int n = 0; n < NR; ++n) bfv[n] = *(const short8*)(lB + boff[n][kk]);
#pragma unroll
      for (int m = 0; m < MR; ++m)
#pragma unroll
        for (int n = 0; n < NR; ++n)
          acc[m][n] = __builtin_amdgcn_mfma_f32_16x16x32_bf16(
              af[m], bfv[n], acc[m][n], 0, 0, 0);
    }
  };

  // ---- Prologue: buf0 <- {A(0),B(0)}; A(1) left in flight ----
  glB(0, 0);
  gloadA(av0, 0);
  lstoreA(av0, 0);                 // auto vmcnt(0) before f2bf: drains B(0) too
  gloadA(av1, 1);                  // queue: [A(1) x4]
  asm volatile("s_waitcnt lgkmcnt(0)" ::: "memory");
  __builtin_amdgcn_s_barrier();
  __builtin_amdgcn_sched_barrier(0);

  static_assert((KSTEPS & 1) == 0, "KSTEPS must be even");
  for (int s = 0; s + 2 < KSTEPS; s += 2) {
    // even: compute step s (buf0); stage {A,B}(s+1)->buf1; issue A(s+2)
    glB(s + 1, 1);                 // queue: [A(s+1), B(s+1)]
    gloadA(av0, s + 2);            // queue: [A(s+1), B(s+1), A(s+2)]
    compute(0);
    lstoreA(av1, 1);               // auto counted vmcnt(NB+4): waits A(s+1)
    asm volatile("s_waitcnt vmcnt(4) lgkmcnt(0)" ::: "memory");
    __builtin_amdgcn_s_barrier();  // A(s+2) stays in flight across barrier
    __builtin_amdgcn_sched_barrier(0);
    // odd: compute step s+1 (buf1); stage (s+2)->buf0; issue A(s+3)
    glB(s + 2, 0);
    gloadA(av1, s + 3);
    compute(1);
    lstoreA(av0, 0);
    asm volatile("s_waitcnt vmcnt(4) lgkmcnt(0)" ::: "memory");
    __builtin_amdgcn_s_barrier();
    __builtin_amdgcn_sched_barrier(0);
  }

  // ---- Epilogue: steps KSTEPS-2, KSTEPS-1 (buf0 ready; av1 = A(last)) ----
  glB(KSTEPS - 1, 1);
  compute(0);
  lstoreA(av1, 1);                 // auto wait for A(last)
  asm volatile("s_waitcnt vmcnt(0) lgkmcnt(0)" ::: "memory");
  __builtin_amdgcn_s_barrier();
  __builtin_amdgcn_sched_barrier(0);
  compute(1);

  float* pout = part + ((size_t)split * NROW + (size_t)bm * BM) * H;
#pragma unroll
  for (int m = 0; m < MR; ++m) {
    const int row = wm * (MR * 16) + m * 16 + loct * 4;
#pragma unroll
    for (int n = 0; n < NR; ++n) {
      const int col = wn * (NR * 16) + n * 16 + l15;
#pragma unroll
      for (int r = 0; r < 4; ++r)
        pout[(size_t)(row + r) * H + col] = acc[m][n][r];
    }
  }
}

// ------- reduce: sum splits + bias + LN + (leaky) + @Wnext -> t_next^T -------
template <int H, int H2, bool ACT>
__global__ __launch_bounds__(256) void reduce_ln(
    const float* __restrict__ part, const float* __restrict__ bias,
    const float* __restrict__ g, const float* __restrict__ be,
    const float* __restrict__ Wn, unsigned short* __restrict__ tT) {
  __shared__ float sW[H * H2];
  __shared__ float sh[4][H];
  const int t = threadIdx.x;
  for (int i = t; i < H * H2; i += 256) sW[i] = Wn[i];
  __syncthreads();

  const int wid = t >> 6, lane = t & 63;
  const int row = blockIdx.x * 4 + wid;
  constexpr int CPL = H / 64;
  float v[CPL];
#pragma unroll
  for (int c = 0; c < CPL; ++c) {
    const int col = lane + c * 64;
    float s = bias[col];
#pragma unroll
    for (int sp = 0; sp < 4; ++sp)
      s += part[((size_t)sp * NROW + row) * H + col];
    v[c] = s;
  }
  float sum = 0;
#pragma unroll
  for (int c = 0; c < CPL; ++c) sum += v[c];
#pragma unroll
  for (int o = 32; o > 0; o >>= 1) sum += __shfl_xor(sum, o);
  const float mu = sum / H;
  float vs = 0;
#pragma unroll
  for (int c = 0; c < CPL; ++c) { float d = v[c] - mu; vs += d * d; }
#pragma unroll
  for (int o = 32; o > 0; o >>= 1) vs += __shfl_xor(vs, o);
  const float rstd = rsqrtf(vs / H + 1e-5f);
#pragma unroll
  for (int c = 0; c < CPL; ++c) {
    const int col = lane + c * 64;
    float h = (v[c] - mu) * rstd * g[col] + be[col];
    if (ACT) h = (h > 0.f) ? h : 0.01f * h;
    sh[wid][col] = h;
  }
  __syncthreads();
  if (lane < H2) {
    float d = 0;
#pragma unroll 8
    for (int k = 0; k < H; ++k) d += sh[wid][k] * sW[k * H2 + lane];
    tT[(size_t)lane * NROW + row] = f2bf(d);
  }
}

// ------- final: sum splits + bias + LN + leaky + @Wl+bl + log_softmax -------
__global__ __launch_bounds__(256) void reduce_final(
    const float* __restrict__ part, const float* __restrict__ bias,
    const float* __restrict__ g, const float* __restrict__ be,
    const float* __restrict__ Wl, const float* __restrict__ bl,
    float* __restrict__ out) {
  __shared__ float sW[32 * 20];
  __shared__ float sbl[20];
  __shared__ float sh[4][32];
  __shared__ float sl[4][20];
  const int t = threadIdx.x;
  for (int i = t; i < 640; i += 256) sW[i] = Wl[i];
  if (t < 20) sbl[t] = bl[t];
  __syncthreads();
  const int wid = t >> 6, lane = t & 63;
  const int row = blockIdx.x * 4 + wid;
  const int col = lane & 31;  // lanes 32..63 duplicate cols 0..31
  float v = bias[col];
#pragma unroll
  for (int sp = 0; sp < 4; ++sp)
    v += part[((size_t)sp * NROW + row) * 32 + col];
  float sum = v;
#pragma unroll
  for (int o = 32; o > 0; o >>= 1) sum += __shfl_xor(sum, o);
  const float mu = sum / 64.f;  // values duplicated 2x across the wave
  float d0 = v - mu;
  float vs = d0 * d0;
#pragma unroll
  for (int o = 32; o > 0; o >>= 1) vs += __shfl_xor(vs, o);
  const float rstd = rsqrtf(vs / 64.f + 1e-5f);
  float h = (v - mu) * rstd * g[col] + be[col];
  h = (h > 0.f) ? h : 0.01f * h;
  if (lane < 32) sh[wid][col] = h;
  __syncthreads();
  if (lane < 20) {
    float lg = sbl[lane];
#pragma unroll
    for (int k = 0; k < 32; ++k) lg += sh[wid][k] * sW[k * 20 + lane];
    sl[wid][lane] = lg;
  }
  __syncthreads();
  if (lane < 20) {
    float mx = -1e30f;
#pragma unroll
    for (int k = 0; k < 20; ++k) mx = fmaxf(mx, sl[wid][k]);
    float se = 0.f;
#pragma unroll
    for (int k = 0; k < 20; ++k) se += expf(sl[wid][k] - mx);
    out[(size_t)row * 20 + lane] = sl[wid][lane] - mx - logf(se);
  }
}

extern "C" void kernel_launch(void* const* d_in, const int* in_sizes, int n_in,
                              void* d_out, int out_size, void* d_ws,
                              size_t ws_size, hipStream_t stream) {
  const float* x    = (const float*)d_in[0];
  const float* adj0 = (const float*)d_in[1];
  const float* adj1 = (const float*)d_in[2];
  const float* adj2 = (const float*)d_in[3];
  const float* W0   = (const float*)d_in[4];
  const float* b0   = (const float*)d_in[5];
  const float* W1   = (const float*)d_in[6];
  const float* b1   = (const float*)d_in[7];
  const float* W2   = (const float*)d_in[8];
  const float* b2   = (const float*)d_in[9];
  const float* g0   = (const float*)d_in[10];
  const float* be0  = (const float*)d_in[11];
  const float* g1   = (const float*)d_in[12];
  const float* be1  = (const float*)d_in[13];
  const float* g2   = (const float*)d_in[14];
  const float* be2  = (const float*)d_in[15];
  const float* Wl   = (const float*)d_in[16];
  const float* bl   = (const float*)d_in[17];
  float* out = (float*)d_out;

  char* ws = (char*)d_ws;
  float* part =          (float*)(ws);                      // 4*12288*128*4 = 25165824 B
  unsigned short* t0T = (unsigned short*)(ws + 25165824);   // 128*12288*2 = 3145728 B
  unsigned short* t1T = (unsigned short*)(ws + 25165824 + 3145728);          // 1572864 B
  unsigned short* t2T = (unsigned short*)(ws + 25165824 + 3145728 + 1572864); // 786432 B

  xw_kernel<<<NROW / 16, 256, 0, stream>>>(x, W0, t0T);
  gcn_gemm<128><<<(NROW / 64) * 4, 256, 0, stream>>>(adj0, t0T, part);
  reduce_ln<128, 64, false><<<NROW / 4, 256, 0, stream>>>(part, b0, g0, be0, W1, t1T);
  gcn_gemm<64><<<(NROW / 64) * 4, 256, 0, stream>>>(adj1, t1T, part);
  reduce_ln<64, 32, true><<<NROW / 4, 256, 0, stream>>>(part, b1, g1, be1, W2, t2T);
  gcn_gemm<32><<<(NROW / 64) * 4, 256, 0, stream>>>(adj2, t2T, part);
  reduce_final<<<NROW / 4, 256, 0, stream>>>(part, b2, g2, be2, Wl, bl, out);
}